// Round 1
// 232.064 us; speedup vs baseline: 1.0010x; 1.0010x over previous
//
#include <hip/hip_runtime.h>
#include <cstddef>

// RNN: h_t = tanh(x_t @ W_ih^T + b_ih + h_{t-1} @ W_hh^T + b_hh), return h_T.
// B=4096, T=512, IN=15, H=20.  3 batches per 64-lane wave, lane = g*20+j,
// wave-synchronous LDS h-swap, zero barriers.
//
// R1 post-mortem: cutting DS ops 10->6 didn't move the bench (233.6->232.3us).
// => not DS-throughput-bound. All 1366 waves are co-resident, so wall =
// 512 * per-step chain latency = ~490 cyc/step vs ~200-cyc model. Cause:
// DS queue order was [h write][h reads][x reads] with x-dots FIRST in the
// compute, so every step drained the FULL DS queue (x returns last) before
// any dot issued.
//
// R2: latency-ordered step.
//  - x_t prefetched into REGISTERS one step ahead; x-dots run from regs
//    while the h round-trip is in flight. DS order per step:
//    [h write][h reads][x(t+1) reads] -> h returns earliest (h-dots gate
//    at lgkmcnt(2)), x(t+1) arrives under the tanh tail.
//  - weights/bias pre-scaled by 2*log2(e): tanh = 1-2/(1+exp2(s')) drops
//    the argument mul from the serial chain.
//  - staging stores bank-swizzled (row r at r*32B ^ ((r&4)<<2)): old 32B
//    lane stride was an 8-way conflict (the whole 524k count); swizzle
//    reaches the 8-phase minimum. Reads are wave-broadcast: unaffected.
// Predicted chain: ds write->reads ~130 + h-dots ~16 + reduce 8 + tanh ~30
// + cvt 4 ~= 190 cyc/step.

typedef float g4 __attribute__((ext_vector_type(4), aligned(4)));
typedef float g2 __attribute__((ext_vector_type(2), aligned(4)));
typedef _Float16 h2  __attribute__((ext_vector_type(2)));
typedef _Float16 v8h __attribute__((ext_vector_type(8)));
typedef _Float16 v4h __attribute__((ext_vector_type(4)));

#define TT 512
#define IN 15
#define HD 20
#define CH 32                 // timesteps per staged chunk
#define NCH (TT / CH)         // 16 chunks
#define XROW 16               // halves per x row (15 + zero pad)
#define XGRP (CH * XROW + 16) // 528 halves: group bases 8 banks apart
#define XBUF (3 * XGRP)       // per dbuf
#define HROW 24               // halves per h row -> rows on disjoint banks

#define P2(v, i) __builtin_shufflevector(v, v, 2 * (i), 2 * (i) + 1)
#define FD(acc, p, w) acc = __builtin_amdgcn_fdot2(p, w, acc, false)

// bank-spreading swizzle for x rows, in halves: r*16 ^ ((r&4)<<1).
// Injective (only byte-addr bit4 flips; bits>=5 carry r), and the commit
// stores hit all eight 4-bank groups exactly 8 lanes each (8-phase minimum).
__device__ __forceinline__ int xsw(int r) { return (r << 4) ^ ((r & 4) << 1); }

__global__ __launch_bounds__(64) void rnn_fused(
    const float* __restrict__ feature, const float* __restrict__ W_ih,
    const float* __restrict__ W_hh, const float* __restrict__ b_ih,
    const float* __restrict__ b_hh, float* __restrict__ out, int B) {
  __shared__ __align__(16) _Float16 xh[2 * XBUF];
  __shared__ __align__(16) _Float16 hh[4 * HROW];

  const int lane = threadIdx.x;        // 0..63
  const int g = lane / HD;             // 0..3 (3 = dummy lanes 60..63)
  const int j = lane - g * HD;         // 0..19
  const int gx = (g < 3) ? g : 2;      // dummy lanes read a valid x row
  const int bid = blockIdx.x;
  const int b = bid * 3 + g;

  const float K = 2.8853900817779268f;  // 2*log2(e), folded into weights

  h2 wih[8];
  {
    const float* wr = W_ih + j * IN;
#pragma unroll
    for (int i = 0; i < 7; ++i)
      wih[i] = (h2){(_Float16)(K * wr[2 * i]), (_Float16)(K * wr[2 * i + 1])};
    wih[7] = (h2){(_Float16)(K * wr[14]), (_Float16)0.f};
  }
  h2 whh[10];
  {
    const float* wr = W_hh + j * HD;
#pragma unroll
    for (int i = 0; i < 10; ++i)
      whh[i] = (h2){(_Float16)(K * wr[2 * i]), (_Float16)(K * wr[2 * i + 1])};
  }
  const float bias = K * (b_ih[j] + b_hh[j]);  // f32 acc init, pre-scaled

  // ---- chunk staging: 96 rows (3 groups x 32 t) of 15 f32 -> 16 f16.
  const int grA = lane >> 5;           // 0 or 1
  const int tcA = lane & 31;
  const int bc = B - 1;
  const int bA = min(bid * 3 + grA, bc);
  const int bB = min(bid * 3 + 2, bc);
  const float* baseA = feature + ((size_t)bA * TT + tcA) * IN;
  const float* baseB = feature + ((size_t)bB * TT + tcA) * IN;  // lanes<32

  g4 rA0, rA1, rA2; g2 rA3; float rA4;
  g4 rB0, rB1, rB2; g2 rB3; float rB4;

  auto issue = [&](int t0) {  // coalesced f32 global loads into regs
    const float* s = baseA + (size_t)t0 * IN;
    rA0 = *(const g4*)(s);      rA1 = *(const g4*)(s + 4);
    rA2 = *(const g4*)(s + 8);  rA3 = *(const g2*)(s + 12);
    rA4 = s[14];
    if (lane < 32) {
      const float* s2 = baseB + (size_t)t0 * IN;
      rB0 = *(const g4*)(s2);     rB1 = *(const g4*)(s2 + 4);
      rB2 = *(const g4*)(s2 + 8); rB3 = *(const g2*)(s2 + 12);
      rB4 = s2[14];
    }
  };
  auto commit = [&](int bsel) {  // f32 regs -> f16 LDS rows (swizzled)
    v8h lo = {(_Float16)rA0.x, (_Float16)rA0.y, (_Float16)rA0.z, (_Float16)rA0.w,
              (_Float16)rA1.x, (_Float16)rA1.y, (_Float16)rA1.z, (_Float16)rA1.w};
    v8h hi = {(_Float16)rA2.x, (_Float16)rA2.y, (_Float16)rA2.z, (_Float16)rA2.w,
              (_Float16)rA3.x, (_Float16)rA3.y, (_Float16)rA4,   (_Float16)0.f};
    _Float16* d = xh + bsel * XBUF + grA * XGRP + xsw(tcA);
    *(v8h*)d = lo; *((v8h*)d + 1) = hi;
    if (lane < 32) {
      v8h lo2 = {(_Float16)rB0.x, (_Float16)rB0.y, (_Float16)rB0.z, (_Float16)rB0.w,
                 (_Float16)rB1.x, (_Float16)rB1.y, (_Float16)rB1.z, (_Float16)rB1.w};
      v8h hi2 = {(_Float16)rB2.x, (_Float16)rB2.y, (_Float16)rB2.z, (_Float16)rB2.w,
                 (_Float16)rB3.x, (_Float16)rB3.y, (_Float16)rB4,   (_Float16)0.f};
      _Float16* d2 = xh + bsel * XBUF + 2 * XGRP + xsw(tcA);
      *(v8h*)d2 = lo2; *((v8h*)d2 + 1) = hi2;
    }
  };

  issue(0);
  commit(0);

  // prefetch x(chunk 0, t=0) into regs
  v8h xa, xb;
  {
    const v8h* xp = (const v8h*)(xh + gx * XGRP + xsw(0));
    xa = xp[0]; xb = xp[1];
  }

  // h0 = 0 directly in regs (no LDS init: every half that is ever read is
  // rewritten by all 20 lanes each step before the read).
  v8h ha, hb; v4h hc;
#pragma unroll
  for (int i = 0; i < 8; ++i) { ha[i] = (_Float16)0.f; hb[i] = (_Float16)0.f; }
#pragma unroll
  for (int i = 0; i < 4; ++i) hc[i] = (_Float16)0.f;

  float hn = 0.f;
  const _Float16* hrd = hh + g * HROW;
  _Float16* hwr = hh + g * HROW + j;

  // One timestep. tcn >= 0: also prefetch x row tcn of the current chunk.
  auto step = [&](const _Float16* xg, int tcn) {
    // x-dots from prefetched regs -- no DS dependency, run during h flight.
    float a0 = bias, a1 = 0.f, a2 = 0.f, a3 = 0.f;
    FD(a0, P2(xa, 0), wih[0]); FD(a1, P2(xa, 1), wih[1]);
    FD(a2, P2(xa, 2), wih[2]); FD(a3, P2(xa, 3), wih[3]);
    FD(a0, P2(xb, 0), wih[4]); FD(a1, P2(xb, 1), wih[5]);
    FD(a2, P2(xb, 2), wih[6]); FD(a3, P2(xb, 3), wih[7]);
    // h-dots gate on the h reads issued at the END of the previous step
    // (lgkmcnt(2): the trailing x reads don't block them).
    FD(a0, P2(ha, 0), whh[0]); FD(a1, P2(ha, 1), whh[1]);
    FD(a2, P2(ha, 2), whh[2]); FD(a3, P2(ha, 3), whh[3]);
    FD(a0, P2(hb, 0), whh[4]); FD(a1, P2(hb, 1), whh[5]);
    FD(a2, P2(hb, 2), whh[6]); FD(a3, P2(hb, 3), whh[7]);
    FD(a0, P2(hc, 0), whh[8]); FD(a1, P2(hc, 1), whh[9]);
    float s = (a0 + a1) + (a2 + a3);     // already scaled by 2*log2(e)
    float e = exp2f(s);
    hn = 1.f - 2.f * __builtin_amdgcn_rcpf(1.f + e);  // tanh
    // DS queue this step: [h write][h reads][x(t+1) reads].
    *hwr = (_Float16)hn;                 // same-wave in-order DS: no barrier
    ha = *(const v8h*)hrd;
    hb = *(const v8h*)(hrd + 8);
    hc = *(const v4h*)(hrd + 16);
    if (tcn >= 0) {
      const v8h* xp = (const v8h*)(xg + xsw(tcn));
      xa = xp[0]; xb = xp[1];
    }
  };

  for (int c = 0; c < NCH; ++c) {
    if (c + 1 < NCH) issue((c + 1) * CH);   // global prefetch, covered by loop
    const _Float16* xg = xh + (c & 1) * XBUF + gx * XGRP;
#pragma unroll 4
    for (int tc = 0; tc < CH - 1; ++tc) step(xg, tc + 1);
    step(xg, -1);   // last step of chunk: next chunk's x not staged yet
    if (c + 1 < NCH) {
      commit((c + 1) & 1);   // other dbuf half: safe anywhere in chunk c
      const v8h* xp =
          (const v8h*)(xh + ((c + 1) & 1) * XBUF + gx * XGRP + xsw(0));
      xa = xp[0]; xb = xp[1];   // queued after commit stores: correct data
    }
  }
  if (g < 3 && b < B) out[(size_t)b * HD + j] = hn;
}

extern "C" void kernel_launch(void* const* d_in, const int* in_sizes, int n_in,
                              void* d_out, int out_size, void* d_ws, size_t ws_size,
                              hipStream_t stream) {
  const float* feature = (const float*)d_in[0];
  const float* W_ih    = (const float*)d_in[1];
  const float* W_hh    = (const float*)d_in[2];
  const float* b_ih    = (const float*)d_in[3];
  const float* b_hh    = (const float*)d_in[4];
  float* out = (float*)d_out;
  const int B = in_sizes[0] / (TT * IN);      // 4096
  const int grid = (B + 2) / 3;               // 3 batches per 64-thread block
  rnn_fused<<<grid, 64, 0, stream>>>(feature, W_ih, W_hh, b_ih, b_hh, out, B);
}